// Round 8
// baseline (105.783 us; speedup 1.0000x reference)
//
#include <hip/hip_runtime.h>
#include <hip/hip_bf16.h>

#define BATCH 4096
#define FEAT  64
#define LW    64
#define KH    5
#define KW    9
#define RH    5
#define PADL  4
#define NPOS  41   // p = h*KW+ww, 0..40; p>=41 (h==4, ww>=5) masked to zero
#define NW    16   // waves per block (K-split)
#define MAGIC 0x5ca1ab1e

typedef __attribute__((ext_vector_type(8))) short bf16x8;
typedef __attribute__((ext_vector_type(4))) float f32x4;

__device__ __forceinline__ short f2bf(float x) {
    union { float f; unsigned u; } v; v.f = x;
    unsigned r = v.u + 0x7FFFu + ((v.u >> 16) & 1u);  // RNE
    return (short)(r >> 16);
}

__device__ __forceinline__ bf16x8 cvt8(f32x4 x0, f32x4 x1) {
    union { bf16x8 v; __hip_bfloat162 h[4]; } u;
    u.h[0] = __float22bfloat162_rn(float2{x0[0], x0[1]});
    u.h[1] = __float22bfloat162_rn(float2{x0[2], x0[3]});
    u.h[2] = __float22bfloat162_rn(float2{x1[0], x1[1]});
    u.h[3] = __float22bfloat162_rn(float2{x1[2], x1[3]});
    return u.v;
}

__device__ __forceinline__ bf16x8 cvt8s(const float* w) {
    union { bf16x8 v; __hip_bfloat162 h[4]; } u;
    u.h[0] = __float22bfloat162_rn(float2{w[0], w[1]});
    u.h[1] = __float22bfloat162_rn(float2{w[2], w[3]});
    u.h[2] = __float22bfloat162_rn(float2{w[4], w[5]});
    u.h[3] = __float22bfloat162_rn(float2{w[6], w[7]});
    return u.v;
}

// One wave's position chunk (R5 structure). USE_WT: B-fragments are two 16B
// bf16 loads from pre-transposed Wt (R2-verified addressing). Else: transient
// scalar f32 gathers (R5 fallback).
template<int W, bool USE_WT>
__device__ __forceinline__ void chunk(
    const float* __restrict__ inputs, const float* __restrict__ cache,
    const float* __restrict__ Wgl, const short* __restrict__ Wt,
    int r0, int index_w, bool upd, bool shift, int n, int g,
    f32x4 acc[4])
{
    constexpr int P0 = (NPOS * W) / NW;
    constexpr int P1 = (NPOS * (W + 1)) / NW;

    const long b = r0 + n;
    const float* crow  = cache  + b * (RH * LW * FEAT);
    const float* inrow = inputs + b * FEAT;
    const int k0 = g * 8;

    #pragma unroll
    for (int p = P0; p < P1; ++p) {
        const int h = p / KW, ww = p % KW;               // compile-time
        const int col = index_w - PADL + ww;             // wave-uniform
        const bool is_input = upd && (h == KH - 1) && (ww == PADL);
        const bool zero = (!is_input && (col < 0 || col >= LW))
                       || (!is_input && shift && h == KH - 1);
        if (zero) continue;                              // wave-uniform skip

        const int hh = shift ? h + 1 : h;                // shift => h<KH-1 here
        const float* aptr = is_input ? inrow
                                     : crow + (hh * LW + col) * FEAT;

        f32x4 x0 = *(const f32x4*)(aptr + k0);
        f32x4 x1 = *(const f32x4*)(aptr + k0 + 4);
        f32x4 x2 = *(const f32x4*)(aptr + 32 + k0);
        f32x4 x3 = *(const f32x4*)(aptr + 32 + k0 + 4);
        bf16x8 a0 = cvt8(x0, x1);
        bf16x8 a1 = cvt8(x2, x3);

        if constexpr (USE_WT) {
            const short* wbase = Wt + p * 4096 + n * 64; // Wt[p][f][c]
            #pragma unroll
            for (int ft = 0; ft < 4; ++ft) {
                bf16x8 b0 = *(const bf16x8*)(wbase + ft * 1024 + k0);
                bf16x8 b1 = *(const bf16x8*)(wbase + ft * 1024 + 32 + k0);
                acc[ft] = __builtin_amdgcn_mfma_f32_16x16x32_bf16(a0, b0, acc[ft], 0, 0, 0);
                acc[ft] = __builtin_amdgcn_mfma_f32_16x16x32_bf16(a1, b1, acc[ft], 0, 0, 0);
            }
        } else {
            const float* wb0 = Wgl + p * 4096 + k0 * 64 + n;
            const float* wb1 = wb0 + 32 * 64;
            #pragma unroll
            for (int ft = 0; ft < 4; ++ft) {
                float w0[8], w1[8];
                #pragma unroll
                for (int j = 0; j < 8; ++j) {
                    w0[j] = wb0[j * 64 + ft * 16];
                    w1[j] = wb1[j * 64 + ft * 16];
                }
                bf16x8 b0 = cvt8s(w0);
                bf16x8 b1 = cvt8s(w1);
                acc[ft] = __builtin_amdgcn_mfma_f32_16x16x32_bf16(a0, b0, acc[ft], 0, 0, 0);
                acc[ft] = __builtin_amdgcn_mfma_f32_16x16x32_bf16(a1, b1, acc[ft], 0, 0, 0);
            }
        }
    }
}

template<bool USE_WT>
__global__ __launch_bounds__(1024) void conv_kernel(
    const float* __restrict__ inputs, const float* __restrict__ cache,
    const float* __restrict__ Wgl, const float* __restrict__ bias,
    const int* __restrict__ idxp, float* __restrict__ out,
    short* __restrict__ Wt, int* __restrict__ flags)
{
    __shared__ union {
        short T[64][72];            // phase A transpose scratch (producers)
        float Lacc[NW][16][65];     // phase B K-split partials
    } sh;

    const int t    = threadIdx.x;
    const int lane = t & 63;
    const int wv   = t >> 6;
    const int n    = lane & 15;
    const int g    = lane >> 4;
    const int r0   = blockIdx.x * 16;

    const int index = idxp[0];
    int index_w = ((index % LW) + LW) % LW;
    const bool upd   = index >= 0;
    const bool shift = upd && (index_w == 0);

    if constexpr (USE_WT) {
        // ---- Phase A: blocks 0..44 each produce one position of Wt ----
        const int p = blockIdx.x;
        if (p < KH * KW) {
            const int h = p / KW, ww = p % KW;
            const bool is_input = upd && (h == KH - 1) && (ww == PADL);
            const int col = index_w - PADL + ww;
            const bool zero = (h == KH - 1 && ww >= PADL + 1)       // causal cut
                           || (!is_input && (col < 0 || col >= LW))  // pad col
                           || (!is_input && shift && h == KH - 1);   // shift row
            const float* src = Wgl + p * 4096;
            #pragma unroll
            for (int i = 0; i < 4; ++i) {
                int e = i * 1024 + t;          // (c,f), f fastest: coalesced read
                int c = e >> 6, f = e & 63;
                sh.T[f][c] = zero ? (short)0 : f2bf(src[e]);
            }
            __syncthreads();
            short* dst = Wt + p * 4096;
            #pragma unroll
            for (int i = 0; i < 4; ++i) {
                int e = i * 1024 + t;          // (f,c), c fastest: coalesced write
                dst[e] = sh.T[e >> 6][e & 63];
            }
            __syncthreads();                   // all stores issued block-wide
            if (t == 0) {
                // release-ordered store: orders all prior global writes (agent)
                __hip_atomic_store(&flags[p], MAGIC, __ATOMIC_RELEASE,
                                   __HIP_MEMORY_SCOPE_AGENT);
            }
        }
        // ---- all blocks: wait until Wt is complete ----
        if (t == 0) {
            #pragma unroll 1
            for (int q = 0; q < KH * KW; ++q) {
                while (__hip_atomic_load(&flags[q], __ATOMIC_ACQUIRE,
                                         __HIP_MEMORY_SCOPE_AGENT) != MAGIC) {
                    __builtin_amdgcn_s_sleep(8);
                }
            }
            __builtin_amdgcn_fence(__ATOMIC_ACQUIRE, "agent");
        }
        __syncthreads();
    }

    // ---- Phase B: conv (R5 structure) ----
    f32x4 acc[4] = {{0,0,0,0},{0,0,0,0},{0,0,0,0},{0,0,0,0}};

    switch (wv) {
        case 0:  chunk<0 , USE_WT>(inputs, cache, Wgl, Wt, r0, index_w, upd, shift, n, g, acc); break;
        case 1:  chunk<1 , USE_WT>(inputs, cache, Wgl, Wt, r0, index_w, upd, shift, n, g, acc); break;
        case 2:  chunk<2 , USE_WT>(inputs, cache, Wgl, Wt, r0, index_w, upd, shift, n, g, acc); break;
        case 3:  chunk<3 , USE_WT>(inputs, cache, Wgl, Wt, r0, index_w, upd, shift, n, g, acc); break;
        case 4:  chunk<4 , USE_WT>(inputs, cache, Wgl, Wt, r0, index_w, upd, shift, n, g, acc); break;
        case 5:  chunk<5 , USE_WT>(inputs, cache, Wgl, Wt, r0, index_w, upd, shift, n, g, acc); break;
        case 6:  chunk<6 , USE_WT>(inputs, cache, Wgl, Wt, r0, index_w, upd, shift, n, g, acc); break;
        case 7:  chunk<7 , USE_WT>(inputs, cache, Wgl, Wt, r0, index_w, upd, shift, n, g, acc); break;
        case 8:  chunk<8 , USE_WT>(inputs, cache, Wgl, Wt, r0, index_w, upd, shift, n, g, acc); break;
        case 9:  chunk<9 , USE_WT>(inputs, cache, Wgl, Wt, r0, index_w, upd, shift, n, g, acc); break;
        case 10: chunk<10, USE_WT>(inputs, cache, Wgl, Wt, r0, index_w, upd, shift, n, g, acc); break;
        case 11: chunk<11, USE_WT>(inputs, cache, Wgl, Wt, r0, index_w, upd, shift, n, g, acc); break;
        case 12: chunk<12, USE_WT>(inputs, cache, Wgl, Wt, r0, index_w, upd, shift, n, g, acc); break;
        case 13: chunk<13, USE_WT>(inputs, cache, Wgl, Wt, r0, index_w, upd, shift, n, g, acc); break;
        case 14: chunk<14, USE_WT>(inputs, cache, Wgl, Wt, r0, index_w, upd, shift, n, g, acc); break;
        default: chunk<15, USE_WT>(inputs, cache, Wgl, Wt, r0, index_w, upd, shift, n, g, acc); break;
    }

    // D layout: col f = ft*16+n, row m = g*4+i
    #pragma unroll
    for (int ft = 0; ft < 4; ++ft)
        #pragma unroll
        for (int i = 0; i < 4; ++i)
            sh.Lacc[wv][g * 4 + i][ft * 16 + n] = acc[ft][i];

    __syncthreads();

    // Reduce over the 16 K-chunks: thread t -> (m = wv, f = lane)
    const int m = wv;
    const int f = lane;
    float s = bias[f];
    #pragma unroll
    for (int w2 = 0; w2 < NW; ++w2) s += sh.Lacc[w2][m][f];
    out[(long)(r0 + m) * FEAT + f] = s;
}

extern "C" void kernel_launch(void* const* d_in, const int* in_sizes, int n_in,
                              void* d_out, int out_size, void* d_ws, size_t ws_size,
                              hipStream_t stream) {
    const float* inputs = (const float*)d_in[0];
    const float* cache  = (const float*)d_in[1];
    const float* kern   = (const float*)d_in[2];
    const float* bias   = (const float*)d_in[3];
    const int*   idx    = (const int*)d_in[4];
    float* out = (float*)d_out;

    // d_ws layout: [0,1024) flags, [1024, 1024+368640) Wt
    const size_t ws_needed = 1024 + (size_t)KH * KW * FEAT * FEAT * sizeof(short);
    if (ws_size >= ws_needed) {
        int*   flags = (int*)d_ws;
        short* Wt    = (short*)((char*)d_ws + 1024);
        conv_kernel<true><<<BATCH / 16, 1024, 0, stream>>>(
            inputs, cache, kern, bias, idx, out, Wt, flags);
    } else {
        conv_kernel<false><<<BATCH / 16, 1024, 0, stream>>>(
            inputs, cache, kern, bias, idx, out, nullptr, nullptr);
    }
}

// Round 9
// 16.176 us; speedup vs baseline: 6.5396x; 6.5396x over previous
//
#include <hip/hip_runtime.h>
#include <hip/hip_bf16.h>

#define BATCH 4096
#define FEAT  64
#define LW    64
#define KH    5
#define KW    9
#define RH    5
#define PADL  4
#define NPOS  41   // p = h*KW+ww, 0..40; p>=41 (h==4, ww>=5) masked to zero
#define NHU   82   // half-position units: u = (p, half), 32 channels each
#define NW    16   // waves per block (K-split)

typedef __attribute__((ext_vector_type(8))) short bf16x8;
typedef __attribute__((ext_vector_type(4))) float f32x4;

__device__ __forceinline__ bf16x8 cvt8(f32x4 x0, f32x4 x1) {
    union { bf16x8 v; __hip_bfloat162 h[4]; } u;
    u.h[0] = __float22bfloat162_rn(float2{x0[0], x0[1]});
    u.h[1] = __float22bfloat162_rn(float2{x0[2], x0[3]});
    u.h[2] = __float22bfloat162_rn(float2{x1[0], x1[1]});
    u.h[3] = __float22bfloat162_rn(float2{x1[2], x1[3]});
    return u.v;
}

__device__ __forceinline__ bf16x8 cvt8s(const float* w) {
    union { bf16x8 v; __hip_bfloat162 h[4]; } u;
    u.h[0] = __float22bfloat162_rn(float2{w[0], w[1]});
    u.h[1] = __float22bfloat162_rn(float2{w[2], w[3]});
    u.h[2] = __float22bfloat162_rn(float2{w[4], w[5]});
    u.h[3] = __float22bfloat162_rn(float2{w[6], w[7]});
    return u.v;
}

// One wave's chunk of half-position units. Each unit = 32 channels of one
// position: 2 A-loads + 32 transient W gathers + 4 MFMAs. Small per-unit
// register footprint (fits 2 units in flight under the 128-VGPR cap) lets
// the compiler overlap unit u+1's gathers with unit u's cvt+MFMA.
template<int W>
__device__ __forceinline__ void chunk(
    const float* __restrict__ inputs, const float* __restrict__ cache,
    const float* __restrict__ Wgl,
    int r0, int index_w, bool upd, bool shift, int n, int g,
    f32x4 acc[4])
{
    constexpr int H0 = (NHU * W) / NW;
    constexpr int H1 = (NHU * (W + 1)) / NW;

    const long b = r0 + n;
    const float* crow  = cache  + b * (RH * LW * FEAT);
    const float* inrow = inputs + b * FEAT;
    const int k0 = g * 8;

    #pragma unroll
    for (int u = H0; u < H1; ++u) {
        const int p    = u >> 1;                         // compile-time
        const int half = u & 1;
        const int h = p / KW, ww = p % KW;               // compile-time
        const int col = index_w - PADL + ww;             // wave-uniform
        const bool is_input = upd && (h == KH - 1) && (ww == PADL);
        const bool zero = (!is_input && (col < 0 || col >= LW))
                       || (!is_input && shift && h == KH - 1);
        if (zero) continue;                              // wave-uniform skip

        const int hh = shift ? h + 1 : h;                // shift => h<KH-1 here
        const float* aptr = is_input ? inrow
                                     : crow + (hh * LW + col) * FEAT;

        const int coff = half * 32 + k0;                 // this unit's c-base
        f32x4 x0 = *(const f32x4*)(aptr + coff);
        f32x4 x1 = *(const f32x4*)(aptr + coff + 4);
        bf16x8 a0 = cvt8(x0, x1);

        // B element (j, ft) = W[p][coff + j][ft*16 + n]
        const float* wb = Wgl + p * 4096 + coff * 64 + n;
        #pragma unroll
        for (int ft = 0; ft < 4; ++ft) {
            float w0[8];
            #pragma unroll
            for (int j = 0; j < 8; ++j)
                w0[j] = wb[j * 64 + ft * 16];            // imm offsets
            bf16x8 b0 = cvt8s(w0);
            acc[ft] = __builtin_amdgcn_mfma_f32_16x16x32_bf16(a0, b0, acc[ft], 0, 0, 0);
        }
    }
}

__global__ __launch_bounds__(1024) void conv_kernel(
    const float* __restrict__ inputs, const float* __restrict__ cache,
    const float* __restrict__ Wgl, const float* __restrict__ bias,
    const int* __restrict__ idxp, float* __restrict__ out)
{
    __shared__ float Lacc[NW][16][65];   // 66.5 KB K-split partials

    const int t    = threadIdx.x;
    const int lane = t & 63;
    const int wv   = t >> 6;             // 0..15 = K-chunk id
    const int n    = lane & 15;          // A row offset (m) and B col offset (f)
    const int g    = lane >> 4;          // k-group
    const int r0   = blockIdx.x * 16;

    const int index = idxp[0];
    int index_w = ((index % LW) + LW) % LW;
    const bool upd   = index >= 0;
    const bool shift = upd && (index_w == 0);

    f32x4 acc[4] = {{0,0,0,0},{0,0,0,0},{0,0,0,0},{0,0,0,0}};

    switch (wv) {
        case 0:  chunk<0 >(inputs, cache, Wgl, r0, index_w, upd, shift, n, g, acc); break;
        case 1:  chunk<1 >(inputs, cache, Wgl, r0, index_w, upd, shift, n, g, acc); break;
        case 2:  chunk<2 >(inputs, cache, Wgl, r0, index_w, upd, shift, n, g, acc); break;
        case 3:  chunk<3 >(inputs, cache, Wgl, r0, index_w, upd, shift, n, g, acc); break;
        case 4:  chunk<4 >(inputs, cache, Wgl, r0, index_w, upd, shift, n, g, acc); break;
        case 5:  chunk<5 >(inputs, cache, Wgl, r0, index_w, upd, shift, n, g, acc); break;
        case 6:  chunk<6 >(inputs, cache, Wgl, r0, index_w, upd, shift, n, g, acc); break;
        case 7:  chunk<7 >(inputs, cache, Wgl, r0, index_w, upd, shift, n, g, acc); break;
        case 8:  chunk<8 >(inputs, cache, Wgl, r0, index_w, upd, shift, n, g, acc); break;
        case 9:  chunk<9 >(inputs, cache, Wgl, r0, index_w, upd, shift, n, g, acc); break;
        case 10: chunk<10>(inputs, cache, Wgl, r0, index_w, upd, shift, n, g, acc); break;
        case 11: chunk<11>(inputs, cache, Wgl, r0, index_w, upd, shift, n, g, acc); break;
        case 12: chunk<12>(inputs, cache, Wgl, r0, index_w, upd, shift, n, g, acc); break;
        case 13: chunk<13>(inputs, cache, Wgl, r0, index_w, upd, shift, n, g, acc); break;
        case 14: chunk<14>(inputs, cache, Wgl, r0, index_w, upd, shift, n, g, acc); break;
        default: chunk<15>(inputs, cache, Wgl, r0, index_w, upd, shift, n, g, acc); break;
    }

    // D layout: col f = ft*16+n, row m = g*4+i
    #pragma unroll
    for (int ft = 0; ft < 4; ++ft)
        #pragma unroll
        for (int i = 0; i < 4; ++i)
            Lacc[wv][g * 4 + i][ft * 16 + n] = acc[ft][i];

    __syncthreads();

    // Reduce over the 16 K-chunks: thread t -> (m = wv, f = lane)
    const int m = wv;
    const int f = lane;
    float s = bias[f];
    #pragma unroll
    for (int w2 = 0; w2 < NW; ++w2) s += Lacc[w2][m][f];
    out[(long)(r0 + m) * FEAT + f] = s;
}

extern "C" void kernel_launch(void* const* d_in, const int* in_sizes, int n_in,
                              void* d_out, int out_size, void* d_ws, size_t ws_size,
                              hipStream_t stream) {
    const float* inputs = (const float*)d_in[0];
    const float* cache  = (const float*)d_in[1];
    const float* kern   = (const float*)d_in[2];
    const float* bias   = (const float*)d_in[3];
    const int*   idx    = (const int*)d_in[4];
    float* out = (float*)d_out;

    conv_kernel<<<BATCH / 16, 1024, 0, stream>>>(inputs, cache, kern, bias, idx, out);
}

// Round 10
// 16.058 us; speedup vs baseline: 6.5877x; 1.0074x over previous
//
#include <hip/hip_runtime.h>
#include <hip/hip_bf16.h>

#define BATCH 4096
#define FEAT  64
#define LW    64
#define KH    5
#define KW    9
#define RH    5
#define PADL  4
#define NPOS  41   // p = h*KW+ww, 0..40; p>=41 (h==4, ww>=5) masked to zero
#define NHU   82   // half-position units: u = (p, half), 32 channels each
#define NW    16   // waves per block (K-split)

typedef __attribute__((ext_vector_type(8))) short bf16x8;
typedef __attribute__((ext_vector_type(4))) float f32x4;

__device__ __forceinline__ bf16x8 cvt8(f32x4 x0, f32x4 x1) {
    union { bf16x8 v; __hip_bfloat162 h[4]; } u;
    u.h[0] = __float22bfloat162_rn(float2{x0[0], x0[1]});
    u.h[1] = __float22bfloat162_rn(float2{x0[2], x0[3]});
    u.h[2] = __float22bfloat162_rn(float2{x1[0], x1[1]});
    u.h[3] = __float22bfloat162_rn(float2{x1[2], x1[3]});
    return u.v;
}

__device__ __forceinline__ bf16x8 cvt8s(const float* w) {
    union { bf16x8 v; __hip_bfloat162 h[4]; } u;
    u.h[0] = __float22bfloat162_rn(float2{w[0], w[1]});
    u.h[1] = __float22bfloat162_rn(float2{w[2], w[3]});
    u.h[2] = __float22bfloat162_rn(float2{w[4], w[5]});
    u.h[3] = __float22bfloat162_rn(float2{w[6], w[7]});
    return u.v;
}

// One wave's chunk of half-position units, two phases:
//  phase 1: issue ALL of this wave's HBM A-loads (<=6 units x 2 f32x4 = 48
//           VGPR) so HBM latency overlaps the whole L2 W-gather phase;
//  phase 2: per unit, transient W gathers + cvt + 4 MFMAs (R9-proven).
// All array indices compile-time (full unroll) — no scratch (rule: runtime-
// indexed ext_vector arrays go to scratch).
template<int W>
__device__ __forceinline__ void chunk(
    const float* __restrict__ inputs, const float* __restrict__ cache,
    const float* __restrict__ Wgl,
    int r0, int index_w, bool upd, bool shift, int n, int g,
    f32x4 acc[4])
{
    constexpr int H0 = (NHU * W) / NW;
    constexpr int H1 = (NHU * (W + 1)) / NW;
    constexpr int NU = H1 - H0;

    const long b = r0 + n;
    const float* crow  = cache  + b * (RH * LW * FEAT);
    const float* inrow = inputs + b * FEAT;
    const int k0 = g * 8;

    f32x4 ax[NU][2];

    // ---- phase 1: hoisted A-loads (HBM) ----
    #pragma unroll
    for (int ui = 0; ui < NU; ++ui) {
        const int u    = H0 + ui;
        const int p    = u >> 1;                         // compile-time
        const int half = u & 1;
        const int h = p / KW, ww = p % KW;               // compile-time
        const int col = index_w - PADL + ww;             // wave-uniform
        const bool is_input = upd && (h == KH - 1) && (ww == PADL);
        const bool zero = (!is_input && (col < 0 || col >= LW))
                       || (!is_input && shift && h == KH - 1);
        if (zero) continue;                              // wave-uniform skip

        const int hh = shift ? h + 1 : h;                // shift => h<KH-1 here
        const float* aptr = is_input ? inrow
                                     : crow + (hh * LW + col) * FEAT;
        const int coff = half * 32 + k0;                 // this unit's c-base
        ax[ui][0] = *(const f32x4*)(aptr + coff);
        ax[ui][1] = *(const f32x4*)(aptr + coff + 4);
    }

    // ---- phase 2: W gathers (L2) + MFMA ----
    #pragma unroll
    for (int ui = 0; ui < NU; ++ui) {
        const int u    = H0 + ui;
        const int p    = u >> 1;
        const int half = u & 1;
        const int h = p / KW, ww = p % KW;
        const int col = index_w - PADL + ww;
        const bool is_input = upd && (h == KH - 1) && (ww == PADL);
        const bool zero = (!is_input && (col < 0 || col >= LW))
                       || (!is_input && shift && h == KH - 1);
        if (zero) continue;                              // same skip as phase 1

        bf16x8 a0 = cvt8(ax[ui][0], ax[ui][1]);

        const int coff = half * 32 + k0;
        // B element (j, ft) = W[p][coff + j][ft*16 + n]
        const float* wb = Wgl + p * 4096 + coff * 64 + n;
        #pragma unroll
        for (int ft = 0; ft < 4; ++ft) {
            float w0[8];
            #pragma unroll
            for (int j = 0; j < 8; ++j)
                w0[j] = wb[j * 64 + ft * 16];            // imm offsets
            bf16x8 b0 = cvt8s(w0);
            acc[ft] = __builtin_amdgcn_mfma_f32_16x16x32_bf16(a0, b0, acc[ft], 0, 0, 0);
        }
    }
}

__global__ __launch_bounds__(1024) void conv_kernel(
    const float* __restrict__ inputs, const float* __restrict__ cache,
    const float* __restrict__ Wgl, const float* __restrict__ bias,
    const int* __restrict__ idxp, float* __restrict__ out)
{
    __shared__ float Lacc[NW][16][65];   // 66.5 KB K-split partials

    const int t    = threadIdx.x;
    const int lane = t & 63;
    const int wv   = t >> 6;             // 0..15 = K-chunk id
    const int n    = lane & 15;          // A row offset (m) and B col offset (f)
    const int g    = lane >> 4;          // k-group
    const int r0   = blockIdx.x * 16;

    const int index = idxp[0];
    int index_w = ((index % LW) + LW) % LW;
    const bool upd   = index >= 0;
    const bool shift = upd && (index_w == 0);

    f32x4 acc[4] = {{0,0,0,0},{0,0,0,0},{0,0,0,0},{0,0,0,0}};

    switch (wv) {
        case 0:  chunk<0 >(inputs, cache, Wgl, r0, index_w, upd, shift, n, g, acc); break;
        case 1:  chunk<1 >(inputs, cache, Wgl, r0, index_w, upd, shift, n, g, acc); break;
        case 2:  chunk<2 >(inputs, cache, Wgl, r0, index_w, upd, shift, n, g, acc); break;
        case 3:  chunk<3 >(inputs, cache, Wgl, r0, index_w, upd, shift, n, g, acc); break;
        case 4:  chunk<4 >(inputs, cache, Wgl, r0, index_w, upd, shift, n, g, acc); break;
        case 5:  chunk<5 >(inputs, cache, Wgl, r0, index_w, upd, shift, n, g, acc); break;
        case 6:  chunk<6 >(inputs, cache, Wgl, r0, index_w, upd, shift, n, g, acc); break;
        case 7:  chunk<7 >(inputs, cache, Wgl, r0, index_w, upd, shift, n, g, acc); break;
        case 8:  chunk<8 >(inputs, cache, Wgl, r0, index_w, upd, shift, n, g, acc); break;
        case 9:  chunk<9 >(inputs, cache, Wgl, r0, index_w, upd, shift, n, g, acc); break;
        case 10: chunk<10>(inputs, cache, Wgl, r0, index_w, upd, shift, n, g, acc); break;
        case 11: chunk<11>(inputs, cache, Wgl, r0, index_w, upd, shift, n, g, acc); break;
        case 12: chunk<12>(inputs, cache, Wgl, r0, index_w, upd, shift, n, g, acc); break;
        case 13: chunk<13>(inputs, cache, Wgl, r0, index_w, upd, shift, n, g, acc); break;
        case 14: chunk<14>(inputs, cache, Wgl, r0, index_w, upd, shift, n, g, acc); break;
        default: chunk<15>(inputs, cache, Wgl, r0, index_w, upd, shift, n, g, acc); break;
    }

    // D layout: col f = ft*16+n, row m = g*4+i
    #pragma unroll
    for (int ft = 0; ft < 4; ++ft)
        #pragma unroll
        for (int i = 0; i < 4; ++i)
            Lacc[wv][g * 4 + i][ft * 16 + n] = acc[ft][i];

    __syncthreads();

    // Reduce over the 16 K-chunks: thread t -> (m = wv, f = lane)
    const int m = wv;
    const int f = lane;
    float s = bias[f];
    #pragma unroll
    for (int w2 = 0; w2 < NW; ++w2) s += Lacc[w2][m][f];
    out[(long)(r0 + m) * FEAT + f] = s;
}

extern "C" void kernel_launch(void* const* d_in, const int* in_sizes, int n_in,
                              void* d_out, int out_size, void* d_ws, size_t ws_size,
                              hipStream_t stream) {
    const float* inputs = (const float*)d_in[0];
    const float* cache  = (const float*)d_in[1];
    const float* kern   = (const float*)d_in[2];
    const float* bias   = (const float*)d_in[3];
    const int*   idx    = (const int*)d_in[4];
    float* out = (float*)d_out;

    conv_kernel<<<BATCH / 16, 1024, 0, stream>>>(inputs, cache, kern, bias, idx, out);
}